// Round 4
// baseline (276.158 us; speedup 1.0000x reference)
//
#include <hip/hip_runtime.h>
#include <hip/hip_bf16.h>

constexpr int Bc = 16, Dc = 64, Tc = 4096, Ec = 1024;
constexpr int NROW = Bc * Tc;          // 65536 rows of dim 64
constexpr float DECAYF = 0.99f;
constexpr float OMDF   = 0.01f;
constexpr float EPSF   = 1e-5f;

typedef short bf16x8 __attribute__((ext_vector_type(8)));
typedef float f32x4  __attribute__((ext_vector_type(4)));

// ---- d_out layout (floats, ref return order) ----
constexpr size_t O_EI  = 0;         // embed_idx [B,T,D]   4194304
constexpr size_t O_QX  = 4194304;   // qx [B,D,T]          4194304
constexpr size_t O_IDX = 8388608;   // quantized_idx [B,T]   65536
constexpr size_t O_EMB = 8454144;   // new_embedding [E,D]   65536
constexpr size_t O_ESZ = 8519680;   // new_ema_size [E]       1024
constexpr size_t O_EMW = 8520704;   // new_ema_w [D,E]       65536

// ---- scratch inside d_out's [0, 8388608) floats. Produced by decomp,
// consumed by gemm/esum, only THEN overwritten by the epilogue. ----
constexpr size_t S_XH = 0;          // ushort plane 65536x64 = 2097152 floats
constexpr size_t S_XM = 2097152;
constexpr size_t S_XL = 4194304;
constexpr size_t S_EH = 6291456;    // ushort plane 1024x64 = 32768 floats
constexpr size_t S_EM = 6324224;    // = S_EH + 32768
constexpr size_t S_EL = 6356992;    // = S_EH + 65536
constexpr size_t S_E2 = 6389760;    // 1024 floats
constexpr size_t S_X2 = 6424576;    // 65536 floats (ends 6490112)
constexpr size_t S_P  = 6557696;    // esum partials [16][64][1024] = 1048576
// cw-split argmin partials (inside O_QX overlay, after S_P; consumed by
// esum_partial's fused merge, then overwritten by epilogue's qx writes)
constexpr size_t S_PB0 = 7606272;   // best, half 0 (cw 0..511)    65536
constexpr size_t S_PI0 = 7671808;   // idx,  half 0                65536
constexpr size_t S_PB1 = 7737344;   // best, half 1 (cw 512..1023) 65536
constexpr size_t S_PI1 = 7802880;   // idx,  half 1                65536

// ---- ws layout (floats): counts[0..1024) | (unused) | norm[66560..67584)

__device__ inline unsigned short bf16bits(float v) {
  union { __hip_bfloat16 b; unsigned short u; } c;
  c.b = __float2bfloat16(v);           // RNE
  return c.u;
}
__device__ inline float bf16val(unsigned short u) {
  union { unsigned u32; float f; } c;
  c.u32 = ((unsigned)u) << 16;         // bf16 -> f32 is exact bit expansion
  return c.f;
}
// exact 3-term split: x = h + m + l + eps, |eps| <= 2^-27 |x|
__device__ inline void split3(float x, unsigned short& h, unsigned short& m,
                              unsigned short& l) {
  h = bf16bits(x);
  float r1 = x - bf16val(h);           // exact (Sterbenz)
  m = bf16bits(r1);
  float r2 = r1 - bf16val(m);          // exact
  l = bf16bits(r2);
}

__device__ inline void pack8(unsigned short* s, uint4* dst) {
  uint4 v;
  v.x = (unsigned)s[0] | ((unsigned)s[1] << 16);
  v.y = (unsigned)s[2] | ((unsigned)s[3] << 16);
  v.z = (unsigned)s[4] | ((unsigned)s[5] << 16);
  v.w = (unsigned)s[6] | ((unsigned)s[7] << 16);
  *dst = v;
}

__device__ inline void gl_lds16(const unsigned short* g, unsigned short* l) {
  __builtin_amdgcn_global_load_lds(
      (const __attribute__((address_space(1))) void*)g,
      (__attribute__((address_space(3))) void*)l, 16, 0, 0);
}

// ---- decomp_x: lane=row; coalesced x read; x2 (exact np-pairwise); 3 planes ----
__global__ __launch_bounds__(256) void decomp_x(const float* __restrict__ x,
                                                float* __restrict__ out) {
  const int row = blockIdx.x * 256 + threadIdx.x;
  const int b = row >> 12, t = row & (Tc - 1);
  const float* xrow = x + (size_t)b * Dc * Tc + t;
  float xv[64];
  #pragma unroll
  for (int d = 0; d < Dc; ++d) xv[d] = xrow[(size_t)d * Tc];

  float x2;
  {
    #pragma clang fp contract(off)
    float r[8];
    #pragma unroll
    for (int j = 0; j < 8; ++j) r[j] = xv[j] * xv[j];
    #pragma unroll
    for (int k = 1; k < 8; ++k) {
      #pragma unroll
      for (int j = 0; j < 8; ++j) r[j] += xv[8 * k + j] * xv[8 * k + j];
    }
    x2 = ((r[0] + r[1]) + (r[2] + r[3])) + ((r[4] + r[5]) + (r[6] + r[7]));
  }
  out[S_X2 + row] = x2;

  uint4* ph = (uint4*)((unsigned short*)(out + S_XH) + (size_t)row * 64);
  uint4* pm = (uint4*)((unsigned short*)(out + S_XM) + (size_t)row * 64);
  uint4* pl = (uint4*)((unsigned short*)(out + S_XL) + (size_t)row * 64);
  #pragma unroll
  for (int k = 0; k < 8; ++k) {
    unsigned short hs[8], ms[8], ls[8];
    #pragma unroll
    for (int j = 0; j < 8; ++j) split3(xv[8 * k + j], hs[j], ms[j], ls[j]);
    pack8(hs, ph + k); pack8(ms, pm + k); pack8(ls, pl + k);
  }
}

// ---- decomp_e: thread=codeword; e2; 3 planes; also zeroes counts ----
__global__ __launch_bounds__(256) void decomp_e(const float* __restrict__ emb,
                                                float* __restrict__ out,
                                                float* __restrict__ ws) {
  const int c = blockIdx.x * 256 + threadIdx.x;
  if (c < 1024) ws[c] = 0.0f;          // counts
  if (c >= Ec) return;
  const float* ep = emb + (size_t)c * Dc;
  float ev[64];
  #pragma unroll
  for (int d = 0; d < Dc; ++d) ev[d] = ep[d];

  float e2;
  {
    #pragma clang fp contract(off)
    float r[8];
    #pragma unroll
    for (int j = 0; j < 8; ++j) r[j] = ev[j] * ev[j];
    #pragma unroll
    for (int k = 1; k < 8; ++k) {
      #pragma unroll
      for (int j = 0; j < 8; ++j) r[j] += ev[8 * k + j] * ev[8 * k + j];
    }
    e2 = ((r[0] + r[1]) + (r[2] + r[3])) + ((r[4] + r[5]) + (r[6] + r[7]));
  }
  out[S_E2 + c] = e2;

  uint4* ph = (uint4*)((unsigned short*)(out + S_EH) + (size_t)c * 64);
  uint4* pm = (uint4*)((unsigned short*)(out + S_EM) + (size_t)c * 64);
  uint4* pl = (uint4*)((unsigned short*)(out + S_EL) + (size_t)c * 64);
  #pragma unroll
  for (int k = 0; k < 8; ++k) {
    unsigned short hs[8], ms[8], ls[8];
    #pragma unroll
    for (int j = 0; j < 8; ++j) split3(ev[8 * k + j], hs[j], ms[j], ls[j]);
    pack8(hs, ph + k); pack8(ms, pm + k); pack8(ls, pl + k);
  }
}

// ---- gemm_argmin R16: cw-split for TLP. R12/R13/R14 all pinned at MfmaUtil
// 39-43% because total waves = 2048 = 2/SIMD, all in barrier lockstep; R15
// showed direct global B-reads are an uncoalesced gather (19% MfmaUtil).
// Fix: keep R12's inner geometry VERBATIM (mt=2, 4 chains/wave, 48 MFMA per
// 12 ds_read_b128, stage->__syncthreads->compute) but split the CODEBOOK:
// each block does 256 rows x 512 cws (8 tiles). Grid 512x512thr -> 4096
// waves = 4/SIMD from 2 independent blocks/CU (LDS 48KB); blocks drift so
// one block's score/barrier phase overlaps the other's MFMA burst. Each
// half writes (best,idx) partials; esum_partial's fused merge (strict <,
// half0 wins ties = lower cw) reproduces the sequential first-min exactly
// -> bit-identical idx. ----
constexpr int TW = 64;              // cw per tile
constexpr int NTL_H = 8;            // tiles per half (512 cw)
constexpr int SLOTS = (TW / 16) * 3 * 2 * 64;  // 16B slots per tile = 1536

__global__ __launch_bounds__(512)
__attribute__((amdgpu_waves_per_eu(4)))
void gemm_argmin(float* __restrict__ out) {
  __shared__ alignas(16) unsigned short lbuf[2][SLOTS * 8];  // 2 x 24 KB

  const int tid  = threadIdx.x;       // 0..511
  const int lane = tid & 63;
  const int wave = tid >> 6;          // 0..7
  const int col  = lane & 15;         // MFMA n / C-col
  const int quad = lane >> 4;
  const int cwhalf = blockIdx.x & 1;  // 0: cw 0..511, 1: cw 512..1023
  const int rowblk = blockIdx.x >> 1; // 0..255
  const int rowbase = rowblk * 256 + wave * 32;
  const int cwbase  = cwhalf * (NTL_H * TW);

  const unsigned short* XH = (const unsigned short*)(out + S_XH);
  const unsigned short* XM = (const unsigned short*)(out + S_XM);
  const unsigned short* XL = (const unsigned short*)(out + S_XL);
  const unsigned short* EHu = (const unsigned short*)(out + S_EH);
  const float* E2 = out + S_E2;
  const float* X2 = out + S_X2;

  // stage GLOBAL tile tlg into lbuf[s]: slot = ((nt*3+pl)*2+half)*64 + lane
  auto stage = [&](int tlg, int s) {
    #pragma unroll
    for (int i = 0; i < 3; ++i) {
      int slot = tid + i * 512;       // 0..1535
      int sl   = slot & 63;
      int sub  = slot >> 6;           // 0..23
      int half = sub & 1;
      int pl   = (sub >> 1) % 3;
      int nt   = sub / 6;             // 0..3
      int cw   = tlg * TW + nt * 16 + (sl & 15);
      int q    = sl >> 4;
      const unsigned short* src =
          EHu + (size_t)pl * 65536 + (size_t)cw * 64 + half * 32 + q * 8;
      gl_lds16(src, &lbuf[s][(size_t)slot * 8]);
    }
  };

  bf16x8 a[12];                       // A-frags: a[mt*6 + plane*2 + half]
  #pragma unroll
  for (int mt = 0; mt < 2; ++mt) {
    size_t ao = (size_t)(rowbase + mt * 16 + col) * 64 + quad * 8;
    a[mt * 6 + 0] = *(const bf16x8*)(XH + ao);
    a[mt * 6 + 1] = *(const bf16x8*)(XH + ao + 32);
    a[mt * 6 + 2] = *(const bf16x8*)(XM + ao);
    a[mt * 6 + 3] = *(const bf16x8*)(XM + ao + 32);
    a[mt * 6 + 4] = *(const bf16x8*)(XL + ao);
    a[mt * 6 + 5] = *(const bf16x8*)(XL + ao + 32);
  }
  float x2v[8];
  #pragma unroll
  for (int mt = 0; mt < 2; ++mt)
    #pragma unroll
    for (int r = 0; r < 4; ++r)
      x2v[mt * 4 + r] = X2[rowbase + mt * 16 + quad * 4 + r];

  // keep frags opaque so the allocator cannot rematerialize from global
  #pragma unroll
  for (int i = 0; i < 12; ++i) asm volatile("" : "+v"(a[i]));
  #pragma unroll
  for (int i = 0; i < 8; ++i) asm volatile("" : "+v"(x2v[i]));

  float best[8];
  int bidx[8];
  #pragma unroll
  for (int i = 0; i < 8; ++i) { best[i] = 3.4e38f; bidx[i] = 0; }

  stage(cwbase / TW, 0);

  for (int tl = 0; tl < NTL_H; ++tl) {
    const int tlg = cwbase / TW + tl;
    __syncthreads();                   // stage(tlg) complete (vmcnt drained)
    if (tl + 1 < NTL_H) stage(tlg + 1, (tl + 1) & 1);
    const unsigned short* lb = lbuf[tl & 1];

    #pragma unroll
    for (int np = 0; np < 2; ++np) {   // pairs of N-tiles: (0,1), (2,3)
      bf16x8 b0[6], b1[6];
      #pragma unroll
      for (int pl = 0; pl < 3; ++pl)
        #pragma unroll
        for (int h = 0; h < 2; ++h) {
          b0[pl * 2 + h] = *(const bf16x8*)(
              lb + ((size_t)(((((2 * np + 0) * 3 + pl) * 2 + h)) * 64 + lane)) * 8);
          b1[pl * 2 + h] = *(const bf16x8*)(
              lb + ((size_t)(((((2 * np + 1) * 3 + pl) * 2 + h)) * 64 + lane)) * 8);
        }
      const float e2v0 = E2[tlg * TW + (2 * np + 0) * 16 + col];
      const float e2v1 = E2[tlg * TW + (2 * np + 1) * 16 + col];

      f32x4 acc00 = {0.f, 0.f, 0.f, 0.f};  // rowtile0 x ntile0
      f32x4 acc01 = {0.f, 0.f, 0.f, 0.f};  // rowtile1 x ntile0
      f32x4 acc10 = {0.f, 0.f, 0.f, 0.f};  // rowtile0 x ntile1
      f32x4 acc11 = {0.f, 0.f, 0.f, 0.f};  // rowtile1 x ntile1
      const int PA[6] = {0, 0, 1, 1, 0, 2};   // products hh,hm,mh,mm,hl,lh
      const int PB[6] = {0, 1, 0, 1, 2, 0};
      #pragma unroll
      for (int p = 0; p < 6; ++p) {
        #pragma unroll
        for (int s = 0; s < 2; ++s) {
          bf16x8 a0 = a[PA[p] * 2 + s];
          bf16x8 a1 = a[6 + PA[p] * 2 + s];
          bf16x8 f0 = b0[PB[p] * 2 + s];
          bf16x8 f1 = b1[PB[p] * 2 + s];
          acc00 = __builtin_amdgcn_mfma_f32_16x16x32_bf16(a0, f0, acc00, 0, 0, 0);
          acc10 = __builtin_amdgcn_mfma_f32_16x16x32_bf16(a0, f1, acc10, 0, 0, 0);
          acc01 = __builtin_amdgcn_mfma_f32_16x16x32_bf16(a1, f0, acc01, 0, 0, 0);
          acc11 = __builtin_amdgcn_mfma_f32_16x16x32_bf16(a1, f1, acc11, 0, 0, 0);
        }
      }

      const int cw0 = tlg * TW + (2 * np + 0) * 16 + col;
      const int cw1 = tlg * TW + (2 * np + 1) * 16 + col;
      #pragma unroll
      for (int r = 0; r < 4; ++r) {
        {
          float q = __builtin_fmaf(-2.0f, acc00[r], e2v0);
          q = q + x2v[r];
          if (q < best[r]) { best[r] = q; bidx[r] = cw0; }
        }
        {
          float q = __builtin_fmaf(-2.0f, acc01[r], e2v0);
          q = q + x2v[4 + r];
          if (q < best[4 + r]) { best[4 + r] = q; bidx[4 + r] = cw0; }
        }
        {
          float q = __builtin_fmaf(-2.0f, acc10[r], e2v1);
          q = q + x2v[r];
          if (q < best[r]) { best[r] = q; bidx[r] = cw1; }
        }
        {
          float q = __builtin_fmaf(-2.0f, acc11[r], e2v1);
          q = q + x2v[4 + r];
          if (q < best[4 + r]) { best[4 + r] = q; bidx[4 + r] = cw1; }
        }
      }
    }
  }

  // cross-lane argmin within each 16-lane col group (ties -> lowest cw index)
  const size_t PB = cwhalf ? S_PB1 : S_PB0;
  const size_t PI = cwhalf ? S_PI1 : S_PI0;
  #pragma unroll
  for (int i = 0; i < 8; ++i) {
    float bq = best[i];
    int bi = bidx[i];
    #pragma unroll
    for (int m = 1; m <= 8; m <<= 1) {
      float qo = __shfl_xor(bq, m, 64);
      int io = __shfl_xor(bi, m, 64);
      bool take = (qo < bq) || (qo == bq && io < bi);
      bq = take ? qo : bq;
      bi = take ? io : bi;
    }
    if (col == 0) {
      int mt = i >> 2, r = i & 3;
      int row = rowbase + mt * 16 + quad * 4 + r;
      out[PB + row] = bq;              // C row = quad*4+reg [m89]
      out[PI + row] = (float)bi;
    }
  }
}

// ---- esum_partial: segmented reduction of x into embed_sum via LDS.
// Fused half-merge: final idx = (b1 < b0) ? i1 : i0 (strict <, half0 = lower
// cw wins ties -> identical to sequential ascending-cw first-min). All 16
// s-blocks compute the merge (deterministic); only s==0 writes O_IDX. ----
__global__ __launch_bounds__(512) void esum_partial(float* __restrict__ out,
                                                    float* __restrict__ ws) {
  const int c = blockIdx.x;       // row chunk, 4096 rows
  const int s = blockIdx.y;       // d-slice of 4
  __shared__ float acc[4 * 1025];
  __shared__ float cnt[1024];
  for (int i = threadIdx.x; i < 4 * 1025; i += 512) acc[i] = 0.f;
  if (s == 0)
    for (int i = threadIdx.x; i < 1024; i += 512) cnt[i] = 0.f;
  __syncthreads();

  const unsigned short* XH = (const unsigned short*)(out + S_XH);
  const unsigned short* XM = (const unsigned short*)(out + S_XM);
  const unsigned short* XL = (const unsigned short*)(out + S_XL);

  #pragma unroll 2
  for (int it = 0; it < 8; ++it) {
    const int r = c * 4096 + it * 512 + threadIdx.x;
    const float b0 = out[S_PB0 + r];
    const float b1 = out[S_PB1 + r];
    const int bi = (b1 < b0) ? (int)out[S_PI1 + r] : (int)out[S_PI0 + r];
    if (s == 0) out[O_IDX + r] = (float)bi;
    const size_t off = (size_t)r * 64 + s * 4;
    const uint2 h = *(const uint2*)(XH + off);
    const uint2 m = *(const uint2*)(XM + off);
    const uint2 l = *(const uint2*)(XL + off);

#define DOPAIR(k, HW, MW, LW)                                                  \
    {                                                                          \
      float v0 = (bf16val((unsigned short)(HW)) +                              \
                  bf16val((unsigned short)(MW))) +                             \
                 bf16val((unsigned short)(LW));                                \
      float v1 = (bf16val((unsigned short)((HW) >> 16)) +                      \
                  bf16val((unsigned short)((MW) >> 16))) +                     \
                 bf16val((unsigned short)((LW) >> 16));                        \
      atomicAdd(&acc[(2 * (k) + 0) * 1025 + bi], v0);                          \
      atomicAdd(&acc[(2 * (k) + 1) * 1025 + bi], v1);                          \
    }
    DOPAIR(0, h.x, m.x, l.x)
    DOPAIR(1, h.y, m.y, l.y)
#undef DOPAIR
    if (s == 0) atomicAdd(&cnt[bi], 1.0f);
  }
  __syncthreads();

  float* part = out + S_P + ((size_t)c * 64 + s * 4) * 1024;
  for (int i = threadIdx.x; i < 4096; i += 512)
    part[i] = acc[(i >> 10) * 1025 + (i & 1023)];
  if (s == 0)
    for (int i = threadIdx.x; i < 1024; i += 512)
      atomicAdd(&ws[i], cnt[i]);
}

// ---- finalize_a: ema_size update + normalization (needs only counts) ----
__global__ __launch_bounds__(1024) void finalize_a(
    const float* __restrict__ ema_size, float* __restrict__ ws,
    float* __restrict__ out) {
  const int e = threadIdx.x;
  float ns = DECAYF * ema_size[e] + OMDF * ws[e];
  __shared__ float red[1024];
  red[e] = ns;
  __syncthreads();
  for (int s = 512; s > 0; s >>= 1) {
    if (e < s) red[e] += red[e + s];
    __syncthreads();
  }
  float n = red[0];
  float v = ((ns + EPSF) / (n + (float)Ec * EPSF)) * n;
  out[O_ESZ + e] = v;
  ws[66560 + e] = v;                   // norm
}

// ---- esum_finalize_w: fused esum_reduce + finalize_b ----
__global__ __launch_bounds__(256) void esum_finalize_w(
    const float* __restrict__ ema_w, const float* __restrict__ ws,
    float* __restrict__ out) {
  const int i = blockIdx.x * 256 + threadIdx.x;  // 0..65535 (= d*1024+e)
  float v = 0.f;
  #pragma unroll
  for (int c = 0; c < 16; ++c) v += out[S_P + (size_t)c * 65536 + i];
  int d = i >> 10;
  int e = i & (Ec - 1);
  float w = DECAYF * ema_w[i] + OMDF * v;
  out[O_EMW + i] = w;
  out[O_EMB + e * Dc + d] = w / ws[66560 + e];
}

// ---- epilogue: pure streaming: read x/idx, gather emb, write embed_idx+qx ----
__global__ __launch_bounds__(256) void epilogue_kernel(
    const float* __restrict__ x, const float* __restrict__ emb,
    float* __restrict__ out) {
  const int row = blockIdx.x * 256 + threadIdx.x;
  const int b = row >> 12, t = row & (Tc - 1);
  const float* xrow = x + (size_t)b * Dc * Tc + t;

  const int bi = (int)out[O_IDX + row];

  const float4* eb = (const float4*)(emb + (size_t)bi * Dc);
  float* qx_base = out + O_QX + (size_t)b * Dc * Tc + t;
  float4* ei_base = (float4*)(out + O_EI + (size_t)row * Dc);

  #pragma unroll
  for (int k = 0; k < 16; ++k) {
    float4 ev = eb[k];
    ei_base[k] = ev;
    {
      const int d = 4 * k + 0; float xd = xrow[(size_t)d * Tc];
      float diff = ev.x - xd;
      qx_base[(size_t)d * Tc] = xd + diff;
    }
    {
      const int d = 4 * k + 1; float xd = xrow[(size_t)d * Tc];
      float diff = ev.y - xd;
      qx_base[(size_t)d * Tc] = xd + diff;
    }
    {
      const int d = 4 * k + 2; float xd = xrow[(size_t)d * Tc];
      float diff = ev.z - xd;
      qx_base[(size_t)d * Tc] = xd + diff;
    }
    {
      const int d = 4 * k + 3; float xd = xrow[(size_t)d * Tc];
      float diff = ev.w - xd;
      qx_base[(size_t)d * Tc] = xd + diff;
    }
  }
}

extern "C" void kernel_launch(void* const* d_in, const int* in_sizes, int n_in,
                              void* d_out, int out_size, void* d_ws, size_t ws_size,
                              hipStream_t stream) {
  const float* x        = (const float*)d_in[0];
  const float* emb      = (const float*)d_in[1];
  const float* ema_size = (const float*)d_in[2];
  const float* ema_w    = (const float*)d_in[3];
  float* out = (float*)d_out;
  float* ws  = (float*)d_ws;

  decomp_x<<<NROW / 256, 256, 0, stream>>>(x, out);
  decomp_e<<<Ec / 256, 256, 0, stream>>>(emb, out, ws);   // also zeroes counts
  gemm_argmin<<<NROW / 128, 512, 0, stream>>>(out);       // 512 blocks: rowblk x cwhalf
  esum_partial<<<dim3(16, 16), 512, 0, stream>>>(out, ws);
  finalize_a<<<1, 1024, 0, stream>>>(ema_size, ws, out);
  esum_finalize_w<<<Ec * Dc / 256, 256, 0, stream>>>(ema_w, ws, out);
  epilogue_kernel<<<NROW / 256, 256, 0, stream>>>(x, emb, out);
}

// Round 5
// 188.937 us; speedup vs baseline: 1.4616x; 1.4616x over previous
//
#include <hip/hip_runtime.h>
#include <hip/hip_bf16.h>

constexpr int Bc = 16, Dc = 64, Tc = 4096, Ec = 1024;
constexpr int NROW = Bc * Tc;          // 65536 rows of dim 64
constexpr float DECAYF = 0.99f;
constexpr float OMDF   = 0.01f;
constexpr float EPSF   = 1e-5f;

typedef short bf16x8 __attribute__((ext_vector_type(8)));
typedef float f32x4  __attribute__((ext_vector_type(4)));

// ---- d_out layout (floats, ref return order) ----
constexpr size_t O_EI  = 0;         // embed_idx [B,T,D]   4194304
constexpr size_t O_QX  = 4194304;   // qx [B,D,T]          4194304
constexpr size_t O_IDX = 8388608;   // quantized_idx [B,T]   65536
constexpr size_t O_EMB = 8454144;   // new_embedding [E,D]   65536
constexpr size_t O_ESZ = 8519680;   // new_ema_size [E]       1024
constexpr size_t O_EMW = 8520704;   // new_ema_w [D,E]       65536

// ---- scratch inside d_out's [0, 8388608) floats. Produced by decomp,
// consumed by gemm/esum, only THEN overwritten by the epilogue. ----
constexpr size_t S_XH = 0;          // ushort plane 65536x64 = 2097152 floats
constexpr size_t S_XM = 2097152;
constexpr size_t S_XL = 4194304;
constexpr size_t S_EH = 6291456;    // ushort plane 1024x64 = 32768 floats
constexpr size_t S_EM = 6324224;    // = S_EH + 32768
constexpr size_t S_EL = 6356992;    // = S_EH + 65536
constexpr size_t S_E2 = 6389760;    // 1024 floats
constexpr size_t S_X2 = 6424576;    // 65536 floats (ends 6490112)
constexpr size_t S_P  = 6557696;    // esum partials [16][64][1024] = 1048576

// ---- ws layout (floats): counts[0..1024) | (unused) | norm[66560..67584)

__device__ inline unsigned short bf16bits(float v) {
  union { __hip_bfloat16 b; unsigned short u; } c;
  c.b = __float2bfloat16(v);           // RNE
  return c.u;
}
__device__ inline float bf16val(unsigned short u) {
  union { unsigned u32; float f; } c;
  c.u32 = ((unsigned)u) << 16;         // bf16 -> f32 is exact bit expansion
  return c.f;
}
// exact 3-term split: x = h + m + l + eps, |eps| <= 2^-27 |x|
__device__ inline void split3(float x, unsigned short& h, unsigned short& m,
                              unsigned short& l) {
  h = bf16bits(x);
  float r1 = x - bf16val(h);           // exact (Sterbenz)
  m = bf16bits(r1);
  float r2 = r1 - bf16val(m);          // exact
  l = bf16bits(r2);
}

__device__ inline void pack8(unsigned short* s, uint4* dst) {
  uint4 v;
  v.x = (unsigned)s[0] | ((unsigned)s[1] << 16);
  v.y = (unsigned)s[2] | ((unsigned)s[3] << 16);
  v.z = (unsigned)s[4] | ((unsigned)s[5] << 16);
  v.w = (unsigned)s[6] | ((unsigned)s[7] << 16);
  *dst = v;
}

__device__ inline void gl_lds16(const unsigned short* g, unsigned short* l) {
  __builtin_amdgcn_global_load_lds(
      (const __attribute__((address_space(1))) void*)g,
      (__attribute__((address_space(3))) void*)l, 16, 0, 0);
}

// ---- decomp_x: lane=row; coalesced x read; x2 (exact np-pairwise); 3 planes ----
__global__ __launch_bounds__(256) void decomp_x(const float* __restrict__ x,
                                                float* __restrict__ out) {
  const int row = blockIdx.x * 256 + threadIdx.x;
  const int b = row >> 12, t = row & (Tc - 1);
  const float* xrow = x + (size_t)b * Dc * Tc + t;
  float xv[64];
  #pragma unroll
  for (int d = 0; d < Dc; ++d) xv[d] = xrow[(size_t)d * Tc];

  float x2;
  {
    #pragma clang fp contract(off)
    float r[8];
    #pragma unroll
    for (int j = 0; j < 8; ++j) r[j] = xv[j] * xv[j];
    #pragma unroll
    for (int k = 1; k < 8; ++k) {
      #pragma unroll
      for (int j = 0; j < 8; ++j) r[j] += xv[8 * k + j] * xv[8 * k + j];
    }
    x2 = ((r[0] + r[1]) + (r[2] + r[3])) + ((r[4] + r[5]) + (r[6] + r[7]));
  }
  out[S_X2 + row] = x2;

  uint4* ph = (uint4*)((unsigned short*)(out + S_XH) + (size_t)row * 64);
  uint4* pm = (uint4*)((unsigned short*)(out + S_XM) + (size_t)row * 64);
  uint4* pl = (uint4*)((unsigned short*)(out + S_XL) + (size_t)row * 64);
  #pragma unroll
  for (int k = 0; k < 8; ++k) {
    unsigned short hs[8], ms[8], ls[8];
    #pragma unroll
    for (int j = 0; j < 8; ++j) split3(xv[8 * k + j], hs[j], ms[j], ls[j]);
    pack8(hs, ph + k); pack8(ms, pm + k); pack8(ls, pl + k);
  }
}

// ---- decomp_e: thread=codeword; e2; 3 planes; also zeroes counts ----
__global__ __launch_bounds__(256) void decomp_e(const float* __restrict__ emb,
                                                float* __restrict__ out,
                                                float* __restrict__ ws) {
  const int c = blockIdx.x * 256 + threadIdx.x;
  if (c < 1024) ws[c] = 0.0f;          // counts
  if (c >= Ec) return;
  const float* ep = emb + (size_t)c * Dc;
  float ev[64];
  #pragma unroll
  for (int d = 0; d < Dc; ++d) ev[d] = ep[d];

  float e2;
  {
    #pragma clang fp contract(off)
    float r[8];
    #pragma unroll
    for (int j = 0; j < 8; ++j) r[j] = ev[j] * ev[j];
    #pragma unroll
    for (int k = 1; k < 8; ++k) {
      #pragma unroll
      for (int j = 0; j < 8; ++j) r[j] += ev[8 * k + j] * ev[8 * k + j];
    }
    e2 = ((r[0] + r[1]) + (r[2] + r[3])) + ((r[4] + r[5]) + (r[6] + r[7]));
  }
  out[S_E2 + c] = e2;

  uint4* ph = (uint4*)((unsigned short*)(out + S_EH) + (size_t)c * 64);
  uint4* pm = (uint4*)((unsigned short*)(out + S_EM) + (size_t)c * 64);
  uint4* pl = (uint4*)((unsigned short*)(out + S_EL) + (size_t)c * 64);
  #pragma unroll
  for (int k = 0; k < 8; ++k) {
    unsigned short hs[8], ms[8], ls[8];
    #pragma unroll
    for (int j = 0; j < 8; ++j) split3(ev[8 * k + j], hs[j], ms[j], ls[j]);
    pack8(hs, ph + k); pack8(ms, pm + k); pack8(ls, pl + k);
  }
}

// ---- gemm_argmin R17: R12 structure (the 47us champion) + DEFERRED SCORE.
// Evidence R12-R16: MfmaUtil pinned ~40% at 2 AND 4 waves/SIMD -> occupancy
// is not the limiter. Per-CU budget: MFMA 59.6k cyc, score-VALU 41k cyc,
// measured 113k = near-serial: each np's 80-op score burst depends on the
// MFMAs issued immediately before it, so the wave stalls on the MFMA chain,
// then scores on an idle matrix pipe. Fix (T15 pattern): carry prev-np accs
// in registers; score np(k-1) while np(k)'s MFMAs are in flight (scores are
// independent of in-flight MFMAs -> scheduler interleaves them under MFMA
// execution). First score neutralized branch-free: pacc=-3.4e38 ->
// fma(-2,.,e2)=+inf -> never beats best. Sequence of best/bidx updates is
// verbatim R12 (np ascending, 00/01@cw0 then 10/11@cw1, strict <) ->
// bit-identical idx. R16's spill lesson: stay at waves_per_eu(2,2). ----
constexpr int TW = 64;              // cw per tile; 16 tiles
constexpr int SLOTS = (TW / 16) * 3 * 2 * 64;  // 16B slots per tile = 1536

__global__ __launch_bounds__(512)
__attribute__((amdgpu_waves_per_eu(2, 2)))
void gemm_argmin(float* __restrict__ out) {
  __shared__ alignas(16) unsigned short lbuf[2][SLOTS * 8];  // 2 x 24 KB

  const int tid  = threadIdx.x;       // 0..511
  const int lane = tid & 63;
  const int wave = tid >> 6;          // 0..7
  const int col  = lane & 15;         // MFMA n / C-col
  const int quad = lane >> 4;
  const int rowbase = blockIdx.x * 256 + wave * 32;

  const unsigned short* XH = (const unsigned short*)(out + S_XH);
  const unsigned short* XM = (const unsigned short*)(out + S_XM);
  const unsigned short* XL = (const unsigned short*)(out + S_XL);
  const unsigned short* EHu = (const unsigned short*)(out + S_EH);
  const float* E2 = out + S_E2;
  const float* X2 = out + S_X2;

  // stage tile tl into lbuf[s]: slot = ((nt*3+pl)*2+half)*64 + lane
  auto stage = [&](int tl, int s) {
    #pragma unroll
    for (int i = 0; i < 3; ++i) {
      int slot = tid + i * 512;       // 0..1535
      int sl   = slot & 63;
      int sub  = slot >> 6;           // 0..23
      int half = sub & 1;
      int pl   = (sub >> 1) % 3;
      int nt   = sub / 6;             // 0..3
      int cw   = tl * TW + nt * 16 + (sl & 15);
      int q    = sl >> 4;
      const unsigned short* src =
          EHu + (size_t)pl * 65536 + (size_t)cw * 64 + half * 32 + q * 8;
      gl_lds16(src, &lbuf[s][(size_t)slot * 8]);
    }
  };

  bf16x8 a[12];                       // A-frags: a[mt*6 + plane*2 + half]
  #pragma unroll
  for (int mt = 0; mt < 2; ++mt) {
    size_t ao = (size_t)(rowbase + mt * 16 + col) * 64 + quad * 8;
    a[mt * 6 + 0] = *(const bf16x8*)(XH + ao);
    a[mt * 6 + 1] = *(const bf16x8*)(XH + ao + 32);
    a[mt * 6 + 2] = *(const bf16x8*)(XM + ao);
    a[mt * 6 + 3] = *(const bf16x8*)(XM + ao + 32);
    a[mt * 6 + 4] = *(const bf16x8*)(XL + ao);
    a[mt * 6 + 5] = *(const bf16x8*)(XL + ao + 32);
  }
  float x2v[8];
  #pragma unroll
  for (int mt = 0; mt < 2; ++mt)
    #pragma unroll
    for (int r = 0; r < 4; ++r)
      x2v[mt * 4 + r] = X2[rowbase + mt * 16 + quad * 4 + r];

  // keep frags opaque so the allocator cannot rematerialize from global
  #pragma unroll
  for (int i = 0; i < 12; ++i) asm volatile("" : "+v"(a[i]));
  #pragma unroll
  for (int i = 0; i < 8; ++i) asm volatile("" : "+v"(x2v[i]));

  float best[8];
  int bidx[8];
  #pragma unroll
  for (int i = 0; i < 8; ++i) { best[i] = 3.4e38f; bidx[i] = 0; }

  // deferred-score state: prev np's accs/e2/cw. Init so the first (dummy)
  // score can never win: fma(-2,-3.4e38,e2) -> +inf -> q=+inf -> not < best.
  f32x4 pacc00, pacc01, pacc10, pacc11;
  #pragma unroll
  for (int r = 0; r < 4; ++r) {
    pacc00[r] = -3.4e38f; pacc01[r] = -3.4e38f;
    pacc10[r] = -3.4e38f; pacc11[r] = -3.4e38f;
  }
  float pe20 = 0.f, pe21 = 0.f;
  int pcw0 = 0, pcw1 = 0;

  // score burst, verbatim R12 update order (00/01 @ cw0, then 10/11 @ cw1)
  auto score = [&](const f32x4& s00, const f32x4& s01, const f32x4& s10,
                   const f32x4& s11, float e0, float e1, int c0, int c1) {
    #pragma unroll
    for (int r = 0; r < 4; ++r) {
      {
        float q = __builtin_fmaf(-2.0f, s00[r], e0);
        q = q + x2v[r];
        if (q < best[r]) { best[r] = q; bidx[r] = c0; }
      }
      {
        float q = __builtin_fmaf(-2.0f, s01[r], e0);
        q = q + x2v[4 + r];
        if (q < best[4 + r]) { best[4 + r] = q; bidx[4 + r] = c0; }
      }
      {
        float q = __builtin_fmaf(-2.0f, s10[r], e1);
        q = q + x2v[r];
        if (q < best[r]) { best[r] = q; bidx[r] = c1; }
      }
      {
        float q = __builtin_fmaf(-2.0f, s11[r], e1);
        q = q + x2v[4 + r];
        if (q < best[4 + r]) { best[4 + r] = q; bidx[4 + r] = c1; }
      }
    }
  };

  stage(0, 0);

  for (int tl = 0; tl < Ec / TW; ++tl) {
    __syncthreads();                   // stage(tl) complete (vmcnt drained)
    if (tl + 1 < Ec / TW) stage(tl + 1, (tl + 1) & 1);
    const unsigned short* lb = lbuf[tl & 1];

    #pragma unroll
    for (int np = 0; np < 2; ++np) {   // pairs of N-tiles: (0,1), (2,3)
      bf16x8 b0[6], b1[6];
      #pragma unroll
      for (int pl = 0; pl < 3; ++pl)
        #pragma unroll
        for (int h = 0; h < 2; ++h) {
          b0[pl * 2 + h] = *(const bf16x8*)(
              lb + ((size_t)(((((2 * np + 0) * 3 + pl) * 2 + h)) * 64 + lane)) * 8);
          b1[pl * 2 + h] = *(const bf16x8*)(
              lb + ((size_t)(((((2 * np + 1) * 3 + pl) * 2 + h)) * 64 + lane)) * 8);
        }
      const float e2v0 = E2[tl * TW + (2 * np + 0) * 16 + col];
      const float e2v1 = E2[tl * TW + (2 * np + 1) * 16 + col];

      f32x4 acc00 = {0.f, 0.f, 0.f, 0.f};  // rowtile0 x ntile0
      f32x4 acc01 = {0.f, 0.f, 0.f, 0.f};  // rowtile1 x ntile0
      f32x4 acc10 = {0.f, 0.f, 0.f, 0.f};  // rowtile0 x ntile1
      f32x4 acc11 = {0.f, 0.f, 0.f, 0.f};  // rowtile1 x ntile1
      const int PA[6] = {0, 0, 1, 1, 0, 2};   // products hh,hm,mh,mm,hl,lh
      const int PB[6] = {0, 1, 0, 1, 2, 0};
      #pragma unroll
      for (int p = 0; p < 6; ++p) {
        #pragma unroll
        for (int s = 0; s < 2; ++s) {
          bf16x8 a0 = a[PA[p] * 2 + s];
          bf16x8 a1 = a[6 + PA[p] * 2 + s];
          bf16x8 f0 = b0[PB[p] * 2 + s];
          bf16x8 f1 = b1[PB[p] * 2 + s];
          acc00 = __builtin_amdgcn_mfma_f32_16x16x32_bf16(a0, f0, acc00, 0, 0, 0);
          acc10 = __builtin_amdgcn_mfma_f32_16x16x32_bf16(a0, f1, acc10, 0, 0, 0);
          acc01 = __builtin_amdgcn_mfma_f32_16x16x32_bf16(a1, f0, acc01, 0, 0, 0);
          acc11 = __builtin_amdgcn_mfma_f32_16x16x32_bf16(a1, f1, acc11, 0, 0, 0);
        }
      }

      // score the PREVIOUS np while this np's MFMAs are in flight
      score(pacc00, pacc01, pacc10, pacc11, pe20, pe21, pcw0, pcw1);

      pacc00 = acc00; pacc01 = acc01; pacc10 = acc10; pacc11 = acc11;
      pe20 = e2v0; pe21 = e2v1;
      pcw0 = tl * TW + (2 * np + 0) * 16 + col;
      pcw1 = tl * TW + (2 * np + 1) * 16 + col;
    }
  }

  // drain the pipeline: score the final np
  score(pacc00, pacc01, pacc10, pacc11, pe20, pe21, pcw0, pcw1);

  // cross-lane argmin within each 16-lane col group (ties -> lowest cw index)
  #pragma unroll
  for (int i = 0; i < 8; ++i) {
    float bq = best[i];
    int bi = bidx[i];
    #pragma unroll
    for (int m = 1; m <= 8; m <<= 1) {
      float qo = __shfl_xor(bq, m, 64);
      int io = __shfl_xor(bi, m, 64);
      bool take = (qo < bq) || (qo == bq && io < bi);
      bq = take ? qo : bq;
      bi = take ? io : bi;
    }
    if (col == 0) {
      int mt = i >> 2, r = i & 3;
      int row = rowbase + mt * 16 + quad * 4 + r;
      out[O_IDX + row] = (float)bi;   // C row = quad*4+reg [m89]
    }
  }
}

// ---- esum_partial: segmented reduction of x into embed_sum via LDS. ----
__global__ __launch_bounds__(512) void esum_partial(float* __restrict__ out,
                                                    float* __restrict__ ws) {
  const int c = blockIdx.x;       // row chunk, 4096 rows
  const int s = blockIdx.y;       // d-slice of 4
  __shared__ float acc[4 * 1025];
  __shared__ float cnt[1024];
  for (int i = threadIdx.x; i < 4 * 1025; i += 512) acc[i] = 0.f;
  if (s == 0)
    for (int i = threadIdx.x; i < 1024; i += 512) cnt[i] = 0.f;
  __syncthreads();

  const unsigned short* XH = (const unsigned short*)(out + S_XH);
  const unsigned short* XM = (const unsigned short*)(out + S_XM);
  const unsigned short* XL = (const unsigned short*)(out + S_XL);

  #pragma unroll 2
  for (int it = 0; it < 8; ++it) {
    const int r = c * 4096 + it * 512 + threadIdx.x;
    const int bi = (int)out[O_IDX + r];
    const size_t off = (size_t)r * 64 + s * 4;
    const uint2 h = *(const uint2*)(XH + off);
    const uint2 m = *(const uint2*)(XM + off);
    const uint2 l = *(const uint2*)(XL + off);

#define DOPAIR(k, HW, MW, LW)                                                  \
    {                                                                          \
      float v0 = (bf16val((unsigned short)(HW)) +                              \
                  bf16val((unsigned short)(MW))) +                             \
                 bf16val((unsigned short)(LW));                                \
      float v1 = (bf16val((unsigned short)((HW) >> 16)) +                      \
                  bf16val((unsigned short)((MW) >> 16))) +                     \
                 bf16val((unsigned short)((LW) >> 16));                        \
      atomicAdd(&acc[(2 * (k) + 0) * 1025 + bi], v0);                          \
      atomicAdd(&acc[(2 * (k) + 1) * 1025 + bi], v1);                          \
    }
    DOPAIR(0, h.x, m.x, l.x)
    DOPAIR(1, h.y, m.y, l.y)
#undef DOPAIR
    if (s == 0) atomicAdd(&cnt[bi], 1.0f);
  }
  __syncthreads();

  float* part = out + S_P + ((size_t)c * 64 + s * 4) * 1024;
  for (int i = threadIdx.x; i < 4096; i += 512)
    part[i] = acc[(i >> 10) * 1025 + (i & 1023)];
  if (s == 0)
    for (int i = threadIdx.x; i < 1024; i += 512)
      atomicAdd(&ws[i], cnt[i]);
}

// ---- finalize_a: ema_size update + normalization (needs only counts) ----
__global__ __launch_bounds__(1024) void finalize_a(
    const float* __restrict__ ema_size, float* __restrict__ ws,
    float* __restrict__ out) {
  const int e = threadIdx.x;
  float ns = DECAYF * ema_size[e] + OMDF * ws[e];
  __shared__ float red[1024];
  red[e] = ns;
  __syncthreads();
  for (int s = 512; s > 0; s >>= 1) {
    if (e < s) red[e] += red[e + s];
    __syncthreads();
  }
  float n = red[0];
  float v = ((ns + EPSF) / (n + (float)Ec * EPSF)) * n;
  out[O_ESZ + e] = v;
  ws[66560 + e] = v;                   // norm
}

// ---- esum_finalize_w: fused esum_reduce + finalize_b ----
__global__ __launch_bounds__(256) void esum_finalize_w(
    const float* __restrict__ ema_w, const float* __restrict__ ws,
    float* __restrict__ out) {
  const int i = blockIdx.x * 256 + threadIdx.x;  // 0..65535 (= d*1024+e)
  float v = 0.f;
  #pragma unroll
  for (int c = 0; c < 16; ++c) v += out[S_P + (size_t)c * 65536 + i];
  int d = i >> 10;
  int e = i & (Ec - 1);
  float w = DECAYF * ema_w[i] + OMDF * v;
  out[O_EMW + i] = w;
  out[O_EMB + e * Dc + d] = w / ws[66560 + e];
}

// ---- epilogue: pure streaming: read x/idx, gather emb, write embed_idx+qx ----
__global__ __launch_bounds__(256) void epilogue_kernel(
    const float* __restrict__ x, const float* __restrict__ emb,
    float* __restrict__ out) {
  const int row = blockIdx.x * 256 + threadIdx.x;
  const int b = row >> 12, t = row & (Tc - 1);
  const float* xrow = x + (size_t)b * Dc * Tc + t;

  const int bi = (int)out[O_IDX + row];

  const float4* eb = (const float4*)(emb + (size_t)bi * Dc);
  float* qx_base = out + O_QX + (size_t)b * Dc * Tc + t;
  float4* ei_base = (float4*)(out + O_EI + (size_t)row * Dc);

  #pragma unroll
  for (int k = 0; k < 16; ++k) {
    float4 ev = eb[k];
    ei_base[k] = ev;
    {
      const int d = 4 * k + 0; float xd = xrow[(size_t)d * Tc];
      float diff = ev.x - xd;
      qx_base[(size_t)d * Tc] = xd + diff;
    }
    {
      const int d = 4 * k + 1; float xd = xrow[(size_t)d * Tc];
      float diff = ev.y - xd;
      qx_base[(size_t)d * Tc] = xd + diff;
    }
    {
      const int d = 4 * k + 2; float xd = xrow[(size_t)d * Tc];
      float diff = ev.z - xd;
      qx_base[(size_t)d * Tc] = xd + diff;
    }
    {
      const int d = 4 * k + 3; float xd = xrow[(size_t)d * Tc];
      float diff = ev.w - xd;
      qx_base[(size_t)d * Tc] = xd + diff;
    }
  }
}

extern "C" void kernel_launch(void* const* d_in, const int* in_sizes, int n_in,
                              void* d_out, int out_size, void* d_ws, size_t ws_size,
                              hipStream_t stream) {
  const float* x        = (const float*)d_in[0];
  const float* emb      = (const float*)d_in[1];
  const float* ema_size = (const float*)d_in[2];
  const float* ema_w    = (const float*)d_in[3];
  float* out = (float*)d_out;
  float* ws  = (float*)d_ws;

  decomp_x<<<NROW / 256, 256, 0, stream>>>(x, out);
  decomp_e<<<Ec / 256, 256, 0, stream>>>(emb, out, ws);   // also zeroes counts
  gemm_argmin<<<NROW / 256, 512, 0, stream>>>(out);
  esum_partial<<<dim3(16, 16), 512, 0, stream>>>(out, ws);
  finalize_a<<<1, 1024, 0, stream>>>(ema_size, ws, out);
  esum_finalize_w<<<Ec * Dc / 256, 256, 0, stream>>>(ema_w, ws, out);
  epilogue_kernel<<<NROW / 256, 256, 0, stream>>>(x, emb, out);
}

// Round 6
// 187.878 us; speedup vs baseline: 1.4699x; 1.0056x over previous
//
#include <hip/hip_runtime.h>
#include <hip/hip_bf16.h>

constexpr int Bc = 16, Dc = 64, Tc = 4096, Ec = 1024;
constexpr int NROW = Bc * Tc;          // 65536 rows of dim 64
constexpr float DECAYF = 0.99f;
constexpr float OMDF   = 0.01f;
constexpr float EPSF   = 1e-5f;

typedef short bf16x8 __attribute__((ext_vector_type(8)));
typedef float f32x4  __attribute__((ext_vector_type(4)));

// ---- d_out layout (floats, ref return order) ----
constexpr size_t O_EI  = 0;         // embed_idx [B,T,D]   4194304
constexpr size_t O_QX  = 4194304;   // qx [B,D,T]          4194304
constexpr size_t O_IDX = 8388608;   // quantized_idx [B,T]   65536
constexpr size_t O_EMB = 8454144;   // new_embedding [E,D]   65536
constexpr size_t O_ESZ = 8519680;   // new_ema_size [E]       1024
constexpr size_t O_EMW = 8520704;   // new_ema_w [D,E]       65536

// ---- scratch inside d_out's [0, 8388608) floats. Produced by decomp,
// consumed by gemm/esum, only THEN overwritten by the epilogue. ----
constexpr size_t S_XH = 0;          // ushort plane 65536x64 = 2097152 floats
constexpr size_t S_XM = 2097152;
constexpr size_t S_XL = 4194304;
constexpr size_t S_EH = 6291456;    // ushort plane 1024x64 = 32768 floats
constexpr size_t S_EM = 6324224;    // = S_EH + 32768
constexpr size_t S_EL = 6356992;    // = S_EH + 65536
constexpr size_t S_E2 = 6389760;    // 1024 floats
constexpr size_t S_X2 = 6424576;    // 65536 floats (ends 6490112)
constexpr size_t S_P  = 6557696;    // esum partials [16][64][1024] = 1048576

// ---- ws layout (floats): counts[0..1024) | (unused) | norm[66560..67584)

__device__ inline unsigned short bf16bits(float v) {
  union { __hip_bfloat16 b; unsigned short u; } c;
  c.b = __float2bfloat16(v);           // RNE
  return c.u;
}
__device__ inline float bf16val(unsigned short u) {
  union { unsigned u32; float f; } c;
  c.u32 = ((unsigned)u) << 16;         // bf16 -> f32 is exact bit expansion
  return c.f;
}
// exact 3-term split: x = h + m + l + eps, |eps| <= 2^-27 |x|
__device__ inline void split3(float x, unsigned short& h, unsigned short& m,
                              unsigned short& l) {
  h = bf16bits(x);
  float r1 = x - bf16val(h);           // exact (Sterbenz)
  m = bf16bits(r1);
  float r2 = r1 - bf16val(m);          // exact
  l = bf16bits(r2);
}

__device__ inline void pack8(unsigned short* s, uint4* dst) {
  uint4 v;
  v.x = (unsigned)s[0] | ((unsigned)s[1] << 16);
  v.y = (unsigned)s[2] | ((unsigned)s[3] << 16);
  v.z = (unsigned)s[4] | ((unsigned)s[5] << 16);
  v.w = (unsigned)s[6] | ((unsigned)s[7] << 16);
  *dst = v;
}

__device__ inline void gl_lds16(const unsigned short* g, unsigned short* l) {
  __builtin_amdgcn_global_load_lds(
      (const __attribute__((address_space(1))) void*)g,
      (__attribute__((address_space(3))) void*)l, 16, 0, 0);
}

// ---- decomp_x: lane=row; coalesced x read; x2 (exact np-pairwise); 3 planes ----
__global__ __launch_bounds__(256) void decomp_x(const float* __restrict__ x,
                                                float* __restrict__ out) {
  const int row = blockIdx.x * 256 + threadIdx.x;
  const int b = row >> 12, t = row & (Tc - 1);
  const float* xrow = x + (size_t)b * Dc * Tc + t;
  float xv[64];
  #pragma unroll
  for (int d = 0; d < Dc; ++d) xv[d] = xrow[(size_t)d * Tc];

  float x2;
  {
    #pragma clang fp contract(off)
    float r[8];
    #pragma unroll
    for (int j = 0; j < 8; ++j) r[j] = xv[j] * xv[j];
    #pragma unroll
    for (int k = 1; k < 8; ++k) {
      #pragma unroll
      for (int j = 0; j < 8; ++j) r[j] += xv[8 * k + j] * xv[8 * k + j];
    }
    x2 = ((r[0] + r[1]) + (r[2] + r[3])) + ((r[4] + r[5]) + (r[6] + r[7]));
  }
  out[S_X2 + row] = x2;

  uint4* ph = (uint4*)((unsigned short*)(out + S_XH) + (size_t)row * 64);
  uint4* pm = (uint4*)((unsigned short*)(out + S_XM) + (size_t)row * 64);
  uint4* pl = (uint4*)((unsigned short*)(out + S_XL) + (size_t)row * 64);
  #pragma unroll
  for (int k = 0; k < 8; ++k) {
    unsigned short hs[8], ms[8], ls[8];
    #pragma unroll
    for (int j = 0; j < 8; ++j) split3(xv[8 * k + j], hs[j], ms[j], ls[j]);
    pack8(hs, ph + k); pack8(ms, pm + k); pack8(ls, pl + k);
  }
}

// ---- decomp_e: thread=codeword; e2; 3 planes; also zeroes counts ----
__global__ __launch_bounds__(256) void decomp_e(const float* __restrict__ emb,
                                                float* __restrict__ out,
                                                float* __restrict__ ws) {
  const int c = blockIdx.x * 256 + threadIdx.x;
  if (c < 1024) ws[c] = 0.0f;          // counts
  if (c >= Ec) return;
  const float* ep = emb + (size_t)c * Dc;
  float ev[64];
  #pragma unroll
  for (int d = 0; d < Dc; ++d) ev[d] = ep[d];

  float e2;
  {
    #pragma clang fp contract(off)
    float r[8];
    #pragma unroll
    for (int j = 0; j < 8; ++j) r[j] = ev[j] * ev[j];
    #pragma unroll
    for (int k = 1; k < 8; ++k) {
      #pragma unroll
      for (int j = 0; j < 8; ++j) r[j] += ev[8 * k + j] * ev[8 * k + j];
    }
    e2 = ((r[0] + r[1]) + (r[2] + r[3])) + ((r[4] + r[5]) + (r[6] + r[7]));
  }
  out[S_E2 + c] = e2;

  uint4* ph = (uint4*)((unsigned short*)(out + S_EH) + (size_t)c * 64);
  uint4* pm = (uint4*)((unsigned short*)(out + S_EM) + (size_t)c * 64);
  uint4* pl = (uint4*)((unsigned short*)(out + S_EL) + (size_t)c * 64);
  #pragma unroll
  for (int k = 0; k < 8; ++k) {
    unsigned short hs[8], ms[8], ls[8];
    #pragma unroll
    for (int j = 0; j < 8; ++j) split3(ev[8 * k + j], hs[j], ms[j], ls[j]);
    pack8(hs, ph + k); pack8(ms, pm + k); pack8(ls, pl + k);
  }
}

// ---- gemm_argmin R18: 8 independent MFMA chains per wave. Evidence chain:
// R10->R12 (2->4 chains) was the big win; R13 (4->2 chains) regressed;
// occupancy x2 (R13/R16) and barrier variants (R14) never moved MfmaUtil off
// ~40%. => binding constraint is MFMA dependent-chain latency: at 4 chains,
// same-chain MFMAs issue 4 slots apart -> ~50% pipe ceiling. Fix: fuse the
// two np-pairs; load all 4 N-tiles' B-frags (24 ds_read_b128), one 96-MFMA
// burst over 8 chains (2 row-tiles x 4 N-tiles), issue order cycling all 8
// chains -> dependent-issue distance 8. Per-chain accumulation order (p,s
// ascending) unchanged; score afterward in R12's exact sequence (np=0 then
// np=1; 00/01@cw0 then 10/11@cw1; strict <) -> bit-identical idx. VGPR ~225:
// legal at waves_per_eu(2,2) (256 cap); R16's spill trap avoided. ----
constexpr int TW = 64;              // cw per tile; 16 tiles
constexpr int SLOTS = (TW / 16) * 3 * 2 * 64;  // 16B slots per tile = 1536

__global__ __launch_bounds__(512)
__attribute__((amdgpu_waves_per_eu(2, 2)))
void gemm_argmin(float* __restrict__ out) {
  __shared__ alignas(16) unsigned short lbuf[2][SLOTS * 8];  // 2 x 24 KB

  const int tid  = threadIdx.x;       // 0..511
  const int lane = tid & 63;
  const int wave = tid >> 6;          // 0..7
  const int col  = lane & 15;         // MFMA n / C-col
  const int quad = lane >> 4;
  const int rowbase = blockIdx.x * 256 + wave * 32;

  const unsigned short* XH = (const unsigned short*)(out + S_XH);
  const unsigned short* XM = (const unsigned short*)(out + S_XM);
  const unsigned short* XL = (const unsigned short*)(out + S_XL);
  const unsigned short* EHu = (const unsigned short*)(out + S_EH);
  const float* E2 = out + S_E2;
  const float* X2 = out + S_X2;

  // stage tile tl into lbuf[s]: slot = ((nt*3+pl)*2+half)*64 + lane
  auto stage = [&](int tl, int s) {
    #pragma unroll
    for (int i = 0; i < 3; ++i) {
      int slot = tid + i * 512;       // 0..1535
      int sl   = slot & 63;
      int sub  = slot >> 6;           // 0..23
      int half = sub & 1;
      int pl   = (sub >> 1) % 3;
      int nt   = sub / 6;             // 0..3
      int cw   = tl * TW + nt * 16 + (sl & 15);
      int q    = sl >> 4;
      const unsigned short* src =
          EHu + (size_t)pl * 65536 + (size_t)cw * 64 + half * 32 + q * 8;
      gl_lds16(src, &lbuf[s][(size_t)slot * 8]);
    }
  };

  bf16x8 a[12];                       // A-frags: a[mt*6 + plane*2 + half]
  #pragma unroll
  for (int mt = 0; mt < 2; ++mt) {
    size_t ao = (size_t)(rowbase + mt * 16 + col) * 64 + quad * 8;
    a[mt * 6 + 0] = *(const bf16x8*)(XH + ao);
    a[mt * 6 + 1] = *(const bf16x8*)(XH + ao + 32);
    a[mt * 6 + 2] = *(const bf16x8*)(XM + ao);
    a[mt * 6 + 3] = *(const bf16x8*)(XM + ao + 32);
    a[mt * 6 + 4] = *(const bf16x8*)(XL + ao);
    a[mt * 6 + 5] = *(const bf16x8*)(XL + ao + 32);
  }
  float x2v[8];
  #pragma unroll
  for (int mt = 0; mt < 2; ++mt)
    #pragma unroll
    for (int r = 0; r < 4; ++r)
      x2v[mt * 4 + r] = X2[rowbase + mt * 16 + quad * 4 + r];

  // keep frags opaque so the allocator cannot rematerialize from global
  #pragma unroll
  for (int i = 0; i < 12; ++i) asm volatile("" : "+v"(a[i]));
  #pragma unroll
  for (int i = 0; i < 8; ++i) asm volatile("" : "+v"(x2v[i]));

  float best[8];
  int bidx[8];
  #pragma unroll
  for (int i = 0; i < 8; ++i) { best[i] = 3.4e38f; bidx[i] = 0; }

  stage(0, 0);

  for (int tl = 0; tl < Ec / TW; ++tl) {
    __syncthreads();                   // stage(tl) complete (vmcnt drained)
    if (tl + 1 < Ec / TW) stage(tl + 1, (tl + 1) & 1);
    const unsigned short* lb = lbuf[tl & 1];

    // load ALL 4 N-tiles' B-frags: bb[nt][pl*2+h]
    bf16x8 bb[4][6];
    #pragma unroll
    for (int nt = 0; nt < 4; ++nt)
      #pragma unroll
      for (int pl = 0; pl < 3; ++pl)
        #pragma unroll
        for (int h = 0; h < 2; ++h)
          bb[nt][pl * 2 + h] = *(const bf16x8*)(
              lb + ((size_t)((((nt * 3 + pl) * 2 + h)) * 64 + lane)) * 8);

    float e2v[4];
    #pragma unroll
    for (int nt = 0; nt < 4; ++nt) e2v[nt] = E2[tl * TW + nt * 16 + col];

    // 8 independent chains: acc[mt][nt]; issue cycles through all 8 ->
    // dependent-issue distance 8. Per-chain (p,s) order identical to R12.
    f32x4 acc[2][4];
    #pragma unroll
    for (int mt = 0; mt < 2; ++mt)
      #pragma unroll
      for (int nt = 0; nt < 4; ++nt)
        acc[mt][nt] = f32x4{0.f, 0.f, 0.f, 0.f};

    const int PA[6] = {0, 0, 1, 1, 0, 2};   // products hh,hm,mh,mm,hl,lh
    const int PB[6] = {0, 1, 0, 1, 2, 0};
    #pragma unroll
    for (int p = 0; p < 6; ++p) {
      #pragma unroll
      for (int s = 0; s < 2; ++s) {
        bf16x8 a0 = a[PA[p] * 2 + s];
        bf16x8 a1 = a[6 + PA[p] * 2 + s];
        #pragma unroll
        for (int nt = 0; nt < 4; ++nt)
          acc[0][nt] = __builtin_amdgcn_mfma_f32_16x16x32_bf16(
              a0, bb[nt][PB[p] * 2 + s], acc[0][nt], 0, 0, 0);
        #pragma unroll
        for (int nt = 0; nt < 4; ++nt)
          acc[1][nt] = __builtin_amdgcn_mfma_f32_16x16x32_bf16(
              a1, bb[nt][PB[p] * 2 + s], acc[1][nt], 0, 0, 0);
      }
    }

    // score in R12's exact sequence: np=0 (tiles 0,1) then np=1 (tiles 2,3)
    #pragma unroll
    for (int np = 0; np < 2; ++np) {
      const int i0 = 2 * np, i1 = 2 * np + 1;
      const float e0 = e2v[i0], e1 = e2v[i1];
      const int cw0 = tl * TW + i0 * 16 + col;
      const int cw1 = tl * TW + i1 * 16 + col;
      #pragma unroll
      for (int r = 0; r < 4; ++r) {
        {
          float q = __builtin_fmaf(-2.0f, acc[0][i0][r], e0);
          q = q + x2v[r];
          if (q < best[r]) { best[r] = q; bidx[r] = cw0; }
        }
        {
          float q = __builtin_fmaf(-2.0f, acc[1][i0][r], e0);
          q = q + x2v[4 + r];
          if (q < best[4 + r]) { best[4 + r] = q; bidx[4 + r] = cw0; }
        }
        {
          float q = __builtin_fmaf(-2.0f, acc[0][i1][r], e1);
          q = q + x2v[r];
          if (q < best[r]) { best[r] = q; bidx[r] = cw1; }
        }
        {
          float q = __builtin_fmaf(-2.0f, acc[1][i1][r], e1);
          q = q + x2v[4 + r];
          if (q < best[4 + r]) { best[4 + r] = q; bidx[4 + r] = cw1; }
        }
      }
    }
  }

  // cross-lane argmin within each 16-lane col group (ties -> lowest cw index)
  #pragma unroll
  for (int i = 0; i < 8; ++i) {
    float bq = best[i];
    int bi = bidx[i];
    #pragma unroll
    for (int m = 1; m <= 8; m <<= 1) {
      float qo = __shfl_xor(bq, m, 64);
      int io = __shfl_xor(bi, m, 64);
      bool take = (qo < bq) || (qo == bq && io < bi);
      bq = take ? qo : bq;
      bi = take ? io : bi;
    }
    if (col == 0) {
      int mt = i >> 2, r = i & 3;
      int row = rowbase + mt * 16 + quad * 4 + r;
      out[O_IDX + row] = (float)bi;   // C row = quad*4+reg [m89]
    }
  }
}

// ---- esum_partial: segmented reduction of x into embed_sum via LDS. ----
__global__ __launch_bounds__(512) void esum_partial(float* __restrict__ out,
                                                    float* __restrict__ ws) {
  const int c = blockIdx.x;       // row chunk, 4096 rows
  const int s = blockIdx.y;       // d-slice of 4
  __shared__ float acc[4 * 1025];
  __shared__ float cnt[1024];
  for (int i = threadIdx.x; i < 4 * 1025; i += 512) acc[i] = 0.f;
  if (s == 0)
    for (int i = threadIdx.x; i < 1024; i += 512) cnt[i] = 0.f;
  __syncthreads();

  const unsigned short* XH = (const unsigned short*)(out + S_XH);
  const unsigned short* XM = (const unsigned short*)(out + S_XM);
  const unsigned short* XL = (const unsigned short*)(out + S_XL);

  #pragma unroll 2
  for (int it = 0; it < 8; ++it) {
    const int r = c * 4096 + it * 512 + threadIdx.x;
    const int bi = (int)out[O_IDX + r];
    const size_t off = (size_t)r * 64 + s * 4;
    const uint2 h = *(const uint2*)(XH + off);
    const uint2 m = *(const uint2*)(XM + off);
    const uint2 l = *(const uint2*)(XL + off);

#define DOPAIR(k, HW, MW, LW)                                                  \
    {                                                                          \
      float v0 = (bf16val((unsigned short)(HW)) +                              \
                  bf16val((unsigned short)(MW))) +                             \
                 bf16val((unsigned short)(LW));                                \
      float v1 = (bf16val((unsigned short)((HW) >> 16)) +                      \
                  bf16val((unsigned short)((MW) >> 16))) +                     \
                 bf16val((unsigned short)((LW) >> 16));                        \
      atomicAdd(&acc[(2 * (k) + 0) * 1025 + bi], v0);                          \
      atomicAdd(&acc[(2 * (k) + 1) * 1025 + bi], v1);                          \
    }
    DOPAIR(0, h.x, m.x, l.x)
    DOPAIR(1, h.y, m.y, l.y)
#undef DOPAIR
    if (s == 0) atomicAdd(&cnt[bi], 1.0f);
  }
  __syncthreads();

  float* part = out + S_P + ((size_t)c * 64 + s * 4) * 1024;
  for (int i = threadIdx.x; i < 4096; i += 512)
    part[i] = acc[(i >> 10) * 1025 + (i & 1023)];
  if (s == 0)
    for (int i = threadIdx.x; i < 1024; i += 512)
      atomicAdd(&ws[i], cnt[i]);
}

// ---- finalize_a: ema_size update + normalization (needs only counts) ----
__global__ __launch_bounds__(1024) void finalize_a(
    const float* __restrict__ ema_size, float* __restrict__ ws,
    float* __restrict__ out) {
  const int e = threadIdx.x;
  float ns = DECAYF * ema_size[e] + OMDF * ws[e];
  __shared__ float red[1024];
  red[e] = ns;
  __syncthreads();
  for (int s = 512; s > 0; s >>= 1) {
    if (e < s) red[e] += red[e + s];
    __syncthreads();
  }
  float n = red[0];
  float v = ((ns + EPSF) / (n + (float)Ec * EPSF)) * n;
  out[O_ESZ + e] = v;
  ws[66560 + e] = v;                   // norm
}

// ---- esum_finalize_w: fused esum_reduce + finalize_b ----
__global__ __launch_bounds__(256) void esum_finalize_w(
    const float* __restrict__ ema_w, const float* __restrict__ ws,
    float* __restrict__ out) {
  const int i = blockIdx.x * 256 + threadIdx.x;  // 0..65535 (= d*1024+e)
  float v = 0.f;
  #pragma unroll
  for (int c = 0; c < 16; ++c) v += out[S_P + (size_t)c * 65536 + i];
  int d = i >> 10;
  int e = i & (Ec - 1);
  float w = DECAYF * ema_w[i] + OMDF * v;
  out[O_EMW + i] = w;
  out[O_EMB + e * Dc + d] = w / ws[66560 + e];
}

// ---- epilogue: pure streaming: read x/idx, gather emb, write embed_idx+qx ----
__global__ __launch_bounds__(256) void epilogue_kernel(
    const float* __restrict__ x, const float* __restrict__ emb,
    float* __restrict__ out) {
  const int row = blockIdx.x * 256 + threadIdx.x;
  const int b = row >> 12, t = row & (Tc - 1);
  const float* xrow = x + (size_t)b * Dc * Tc + t;

  const int bi = (int)out[O_IDX + row];

  const float4* eb = (const float4*)(emb + (size_t)bi * Dc);
  float* qx_base = out + O_QX + (size_t)b * Dc * Tc + t;
  float4* ei_base = (float4*)(out + O_EI + (size_t)row * Dc);

  #pragma unroll
  for (int k = 0; k < 16; ++k) {
    float4 ev = eb[k];
    ei_base[k] = ev;
    {
      const int d = 4 * k + 0; float xd = xrow[(size_t)d * Tc];
      float diff = ev.x - xd;
      qx_base[(size_t)d * Tc] = xd + diff;
    }
    {
      const int d = 4 * k + 1; float xd = xrow[(size_t)d * Tc];
      float diff = ev.y - xd;
      qx_base[(size_t)d * Tc] = xd + diff;
    }
    {
      const int d = 4 * k + 2; float xd = xrow[(size_t)d * Tc];
      float diff = ev.z - xd;
      qx_base[(size_t)d * Tc] = xd + diff;
    }
    {
      const int d = 4 * k + 3; float xd = xrow[(size_t)d * Tc];
      float diff = ev.w - xd;
      qx_base[(size_t)d * Tc] = xd + diff;
    }
  }
}

extern "C" void kernel_launch(void* const* d_in, const int* in_sizes, int n_in,
                              void* d_out, int out_size, void* d_ws, size_t ws_size,
                              hipStream_t stream) {
  const float* x        = (const float*)d_in[0];
  const float* emb      = (const float*)d_in[1];
  const float* ema_size = (const float*)d_in[2];
  const float* ema_w    = (const float*)d_in[3];
  float* out = (float*)d_out;
  float* ws  = (float*)d_ws;

  decomp_x<<<NROW / 256, 256, 0, stream>>>(x, out);
  decomp_e<<<Ec / 256, 256, 0, stream>>>(emb, out, ws);   // also zeroes counts
  gemm_argmin<<<NROW / 256, 512, 0, stream>>>(out);
  esum_partial<<<dim3(16, 16), 512, 0, stream>>>(out, ws);
  finalize_a<<<1, 1024, 0, stream>>>(ema_size, ws, out);
  esum_finalize_w<<<Ec * Dc / 256, 256, 0, stream>>>(ema_w, ws, out);
  epilogue_kernel<<<NROW / 256, 256, 0, stream>>>(x, emb, out);
}